// Round 2
// baseline (1105.959 us; speedup 1.0000x reference)
//
#include <hip/hip_runtime.h>
#include <stdint.h>

#define DEV __device__ __forceinline__

typedef __attribute__((ext_vector_type(8))) short short8;
typedef __attribute__((ext_vector_type(8))) __bf16 bf16x8;
typedef __attribute__((ext_vector_type(4))) float f32x4;

DEV unsigned short f2bf(float f) {
  union { float f; unsigned int u; } v; v.f = f;
  unsigned int r = v.u + 0x7fffu + ((v.u >> 16) & 1u);
  return (unsigned short)(r >> 16);
}
DEV float bf2f(unsigned short h) {
  union { unsigned int u; float f; } v; v.u = ((unsigned int)h) << 16;
  return v.f;
}
DEV f32x4 mfma16(short8 a, short8 b, f32x4 c) {
  return __builtin_amdgcn_mfma_f32_16x16x32_bf16(
      __builtin_bit_cast(bf16x8, a), __builtin_bit_cast(bf16x8, b), c, 0, 0, 0);
}
DEV void gload_lds16(const void* g, void* lds) {
  __builtin_amdgcn_global_load_lds(
      (const __attribute__((address_space(1))) void*)g,
      (__attribute__((address_space(3))) void*)lds, 16, 0, 0);
}

// ---------------- abs-mean scale ----------------
__global__ __launch_bounds__(256) void absmean_partial(
    const float* __restrict__ w, int n, float* __restrict__ partial) {
  const float4* w4 = (const float4*)w;
  int n4 = n >> 2;
  float s = 0.f;
  for (int i = blockIdx.x * 256 + threadIdx.x; i < n4; i += 256 * 256) {
    float4 v = w4[i];
    s += fabsf(v.x) + fabsf(v.y) + fabsf(v.z) + fabsf(v.w);
  }
#pragma unroll
  for (int m = 1; m < 64; m <<= 1) s += __shfl_xor(s, m);
  __shared__ float red[4];
  if ((threadIdx.x & 63) == 0) red[threadIdx.x >> 6] = s;
  __syncthreads();
  if (threadIdx.x == 0) partial[blockIdx.x] = red[0] + red[1] + red[2] + red[3];
}

__global__ __launch_bounds__(256) void absmean_final(
    const float* __restrict__ partial, float* __restrict__ scales) {
  __shared__ double red[256];
  const int m = blockIdx.x;
  red[threadIdx.x] = (double)partial[m * 256 + threadIdx.x];
  __syncthreads();
  for (int s = 128; s > 0; s >>= 1) {
    if (threadIdx.x < s) red[threadIdx.x] += red[threadIdx.x + s];
    __syncthreads();
  }
  if (threadIdx.x == 0) {
    const long long cnt = (m < 4) ? 4194304ll : 16777216ll;
    scales[m] = (float)(red[0] / (double)cnt);
  }
}

// ---------------- ternary quantize -> bf16 ----------------
__global__ __launch_bounds__(256) void quantize_w(
    const float* __restrict__ w, unsigned short* __restrict__ out, int n,
    const float* __restrict__ scales, int sidx) {
  const float sc = scales[sidx];
  const float inv = 1.f / (sc + 1e-5f);
  int n4 = n >> 2;
  for (int i = blockIdx.x * 256 + threadIdx.x; i < n4; i += 2048 * 256) {
    float4 v = ((const float4*)w)[i];
    ushort4 o;
    o.x = f2bf(fminf(fmaxf(rintf(v.x * inv), -1.f), 1.f) * sc);
    o.y = f2bf(fminf(fmaxf(rintf(v.y * inv), -1.f), 1.f) * sc);
    o.z = f2bf(fminf(fmaxf(rintf(v.z * inv), -1.f), 1.f) * sc);
    o.w = f2bf(fminf(fmaxf(rintf(v.w * inv), -1.f), 1.f) * sc);
    ((ushort4*)out)[i] = o;
  }
}

// ---------------- RMSNorm (f32 in -> bf16 out) ----------------
__global__ __launch_bounds__(256) void rmsnorm_k(
    const float* __restrict__ x, const float* __restrict__ wt,
    unsigned short* __restrict__ out) {
  const long long t = blockIdx.x;
  const float* xr = x + t * 2048;
  const int i0 = threadIdx.x * 8;
  float4 a = *(const float4*)(xr + i0);
  float4 b = *(const float4*)(xr + i0 + 4);
  float ss = a.x * a.x + a.y * a.y + a.z * a.z + a.w * a.w +
             b.x * b.x + b.y * b.y + b.z * b.z + b.w * b.w;
#pragma unroll
  for (int m = 1; m < 64; m <<= 1) ss += __shfl_xor(ss, m);
  __shared__ float red[4];
  if ((threadIdx.x & 63) == 0) red[threadIdx.x >> 6] = ss;
  __syncthreads();
  float tot = red[0] + red[1] + red[2] + red[3];
  float rs = rsqrtf(tot * (1.f / 2048.f) + 1e-5f);
  float4 wa = *(const float4*)(wt + i0);
  float4 wb = *(const float4*)(wt + i0 + 4);
  ushort4 o1, o2;
  o1.x = f2bf(a.x * wa.x * rs); o1.y = f2bf(a.y * wa.y * rs);
  o1.z = f2bf(a.z * wa.z * rs); o1.w = f2bf(a.w * wa.w * rs);
  o2.x = f2bf(b.x * wb.x * rs); o2.y = f2bf(b.y * wb.y * rs);
  o2.z = f2bf(b.z * wb.z * rs); o2.w = f2bf(b.w * wb.w * rs);
  *(ushort4*)(out + t * 2048 + i0) = o1;
  *(ushort4*)(out + t * 2048 + i0 + 4) = o2;
}

// ---------------- RoPE + V transpose ----------------
// qkv: [4096][6144] bf16 (q|k|v). qr scaled by 1/sqrt(128).
// vt: [2][2048][2048] = per-batch V^T (row d_full, col t)
__global__ __launch_bounds__(256) void rope_k(
    const unsigned short* __restrict__ qkv, const float* __restrict__ cosT,
    const float* __restrict__ sinT, unsigned short* __restrict__ qr,
    unsigned short* __restrict__ kr, unsigned short* __restrict__ vt) {
  const long long gid = (long long)blockIdx.x * 256 + threadIdx.x;
  const int t = (int)(gid >> 10);
  const int r = (int)(gid & 1023);
  const int h = r >> 6, d = r & 63;
  const int s = t & 2047, b = t >> 11;
  const unsigned short* row = qkv + (long long)t * 6144;
  const float c = cosT[s * 128 + d], sn = sinT[s * 128 + d];
  const int col = h * 128 + d;
  const float SC = 0.08838834764831845f;  // 1/sqrt(128)
  float q1 = bf2f(row[col]), q2 = bf2f(row[col + 64]);
  float k1 = bf2f(row[2048 + col]), k2 = bf2f(row[2048 + col + 64]);
  long long ob = (long long)t * 2048 + col;
  qr[ob] = f2bf((q1 * c - q2 * sn) * SC);
  qr[ob + 64] = f2bf((q2 * c + q1 * sn) * SC);
  kr[ob] = f2bf(k1 * c - k2 * sn);
  kr[ob + 64] = f2bf(k2 * c + k1 * sn);
  vt[((long long)b * 2048 + col) * 2048 + s] = row[4096 + col];
  vt[((long long)b * 2048 + col + 64) * 2048 + s] = row[4096 + col + 64];
}

// ---------------- causal row softmax: f32 scores -> bf16 probs ----------------
__global__ __launch_bounds__(256) void softmax_causal(
    const float* __restrict__ scores, unsigned short* __restrict__ probs) {
  const int r = blockIdx.x;  // 0..4095
  const int s = r & 2047;
  const float* src = scores + (long long)r * 2048;
  unsigned short* dst = probs + (long long)r * 2048;
  const int L = s + 1;
  __shared__ float red[4];
  float mx = -1e30f;
  for (int j = threadIdx.x; j < L; j += 256) mx = fmaxf(mx, src[j]);
#pragma unroll
  for (int m = 1; m < 64; m <<= 1) mx = fmaxf(mx, __shfl_xor(mx, m));
  if ((threadIdx.x & 63) == 0) red[threadIdx.x >> 6] = mx;
  __syncthreads();
  mx = fmaxf(fmaxf(red[0], red[1]), fmaxf(red[2], red[3]));
  float sum = 0.f;
  for (int j = threadIdx.x; j < L; j += 256) sum += __expf(src[j] - mx);
  __syncthreads();
#pragma unroll
  for (int m = 1; m < 64; m <<= 1) sum += __shfl_xor(sum, m);
  if ((threadIdx.x & 63) == 0) red[threadIdx.x >> 6] = sum;
  __syncthreads();
  const float inv = 1.f / (red[0] + red[1] + red[2] + red[3]);
  for (int j = threadIdx.x; j < 2048; j += 256)
    dst[j] = (j < L) ? f2bf(__expf(src[j] - mx) * inv) : (unsigned short)0;
}

// ---------------- NT bf16 GEMM: C[M][N] = A[M][K] * B[N][K]^T ----------------
// EPI 0: bf16 out. 1/3: f32 out = Ep(f32)+acc. 2: bf16 out = Ep(bf16)*acc.
// 4: f32 raw out.
// CAUSAL 0: none. 1: skip blocks with n0 > m0+127. 2: K-limit to m0+128.
template <int EPI, int CAUSAL>
__global__ __launch_bounds__(256) void gemm_nt(
    const unsigned short* __restrict__ A, const unsigned short* __restrict__ Bw,
    void* __restrict__ Cp, const void* __restrict__ Ep, int M, int N, int K,
    long long sAz, long long sBz, long long sCz) {
  const long long m0 = (long long)blockIdx.y * 128;
  const long long n0 = (long long)blockIdx.x * 128;
  if (CAUSAL == 1 && n0 > m0 + 127) return;
  __shared__ __align__(16) unsigned short sA[2][128 * 32];
  __shared__ __align__(16) unsigned short sB[2][128 * 32];
  const int tid = threadIdx.x;
  const int w = tid >> 6, l = tid & 63;
  const long long z = blockIdx.z;
  A += z * sAz;
  Bw += z * sBz;
  const long long cofs = z * sCz;
  const int wr = w >> 1, wc = w & 1;
  const int lrow = l & 15, lk = (l >> 4) * 8;

  f32x4 acc[4][4] = {};
  int nk = K >> 5;
  if (CAUSAL == 2) nk = (int)((m0 + 128) >> 5);
  int cur = 0;

  auto stage = [&](int buf, int k0) {
#pragma unroll
    for (int i = 0; i < 2; ++i) {
      const int flat = (w * 2 + i) * 64 + l;  // 16B chunk id, 0..511
      const int row = flat >> 2;
      const int col = (flat & 3) * 8;
      gload_lds16(&A[(m0 + row) * K + k0 + col], (char*)&sA[buf][0] + (w * 2 + i) * 1024);
      gload_lds16(&Bw[(n0 + row) * K + k0 + col], (char*)&sB[buf][0] + (w * 2 + i) * 1024);
    }
  };

  stage(0, 0);
  __syncthreads();
  for (int kt = 0; kt < nk; ++kt) {
    if (kt + 1 < nk) stage(cur ^ 1, (kt + 1) << 5);
    short8 af[4], bfr[4];
#pragma unroll
    for (int m = 0; m < 4; ++m)
      af[m] = *(const short8*)&sA[cur][(wr * 64 + m * 16 + lrow) * 32 + lk];
#pragma unroll
    for (int n = 0; n < 4; ++n)
      bfr[n] = *(const short8*)&sB[cur][(wc * 64 + n * 16 + lrow) * 32 + lk];
#pragma unroll
    for (int m = 0; m < 4; ++m)
#pragma unroll
      for (int n = 0; n < 4; ++n)
        acc[m][n] = mfma16(af[m], bfr[n], acc[m][n]);
    __syncthreads();
    cur ^= 1;
  }

  const int orow = (l >> 4) * 4, ocol = l & 15;
#pragma unroll
  for (int m = 0; m < 4; ++m)
#pragma unroll
    for (int n = 0; n < 4; ++n)
#pragma unroll
      for (int r = 0; r < 4; ++r) {
        long long gr = m0 + wr * 64 + m * 16 + orow + r;
        long long gc = n0 + wc * 64 + n * 16 + ocol;
        long long idx = cofs + gr * N + gc;
        float v = acc[m][n][r];
        if (EPI == 0) {
          ((unsigned short*)Cp)[idx] = f2bf(v);
        } else if (EPI == 1 || EPI == 3) {
          ((float*)Cp)[idx] = ((const float*)Ep)[idx] + v;
        } else if (EPI == 2) {
          ((unsigned short*)Cp)[idx] = f2bf(bf2f(((const unsigned short*)Ep)[idx]) * v);
        } else {  // 4
          ((float*)Cp)[idx] = v;
        }
      }
}

extern "C" void kernel_launch(void* const* d_in, const int* in_sizes, int n_in,
                              void* d_out, int out_size, void* d_ws, size_t ws_size,
                              hipStream_t stream) {
  (void)in_sizes; (void)n_in; (void)out_size; (void)ws_size;
  const float* hidden = (const float*)d_in[0];
  const float* cosT = (const float*)d_in[2];
  const float* sinT = (const float*)d_in[3];
  const float* wq = (const float*)d_in[4];
  const float* wk = (const float*)d_in[5];
  const float* wv = (const float*)d_in[6];
  const float* wo = (const float*)d_in[7];
  const float* wg = (const float*)d_in[8];
  const float* wu = (const float*)d_in[9];
  const float* wd = (const float*)d_in[10];
  const float* ln1 = (const float*)d_in[11];
  const float* ln2 = (const float*)d_in[12];

  const size_t MB = 1ull << 20;
  char* ws = (char*)d_ws;
  // phase-1 (QKV) region
  unsigned short* xn    = (unsigned short*)(ws + 0);        // 16MB [0,16)
  unsigned short* wqkvq = (unsigned short*)(ws + 16 * MB);  // 24MB [16,40)
  unsigned short* qkv   = (unsigned short*)(ws + 40 * MB);  // 48MB [40,88)
  unsigned short* qrb   = (unsigned short*)(ws + 88 * MB);  // 16MB [88,104)
  unsigned short* krb   = (unsigned short*)(ws + 104 * MB); // 16MB [104,120)
  unsigned short* vtb   = (unsigned short*)(ws + 120 * MB); // 16MB [120,136)
  // attention aliases (live after QKV gemm / rope are done)
  float*          scoresB = (float*)(ws + 0);               // 32MB [0,32)  (xn+wqkvq dead)
  unsigned short* probsB  = (unsigned short*)(ws + 40 * MB);// 16MB [40,56) (qkv dead)
  // MLP aliases (live after PV gemm)
  unsigned short* wgq   = (unsigned short*)(ws + 0);        // 32MB [0,32)
  unsigned short* wuq   = (unsigned short*)(ws + 32 * MB);  // 32MB [32,64)
  unsigned short* gbuf  = (unsigned short*)(ws + 64 * MB);  // 64MB [64,128)
  // persistent region
  unsigned short* attnb = (unsigned short*)(ws + 136 * MB); // 16MB
  unsigned short* woq   = (unsigned short*)(ws + 152 * MB); // 8MB
  float*          hbuf  = (float*)(ws + 160 * MB);          // 32MB
  unsigned short* ybuf  = (unsigned short*)(ws + 192 * MB); // 16MB
  unsigned short* gated = (unsigned short*)(ws + 208 * MB); // 64MB
  unsigned short* wdq   = (unsigned short*)(ws + 272 * MB); // 32MB
  float* partials       = (float*)(ws + 304 * MB);
  float* scales         = (float*)(ws + 304 * MB + 16384);

  const float* wptr[7] = {wq, wk, wv, wo, wg, wu, wd};
  const int wn[7] = {4194304, 4194304, 4194304, 4194304, 16777216, 16777216, 16777216};
  for (int m = 0; m < 7; ++m)
    absmean_partial<<<256, 256, 0, stream>>>(wptr[m], wn[m], partials + m * 256);
  absmean_final<<<7, 256, 0, stream>>>(partials, scales);

  quantize_w<<<2048, 256, 0, stream>>>(wo, woq, 4194304, scales, 3);
  quantize_w<<<2048, 256, 0, stream>>>(wd, wdq, 16777216, scales, 6);

  rmsnorm_k<<<4096, 256, 0, stream>>>(hidden, ln1, xn);

  quantize_w<<<2048, 256, 0, stream>>>(wq, wqkvq, 4194304, scales, 0);
  quantize_w<<<2048, 256, 0, stream>>>(wk, wqkvq + 4194304, 4194304, scales, 1);
  quantize_w<<<2048, 256, 0, stream>>>(wv, wqkvq + 8388608, 4194304, scales, 2);

  gemm_nt<0, 0><<<dim3(48, 32, 1), 256, 0, stream>>>(
      xn, wqkvq, qkv, nullptr, 4096, 6144, 2048, 0, 0, 0);

  rope_k<<<16384, 256, 0, stream>>>(qkv, cosT, sinT, qrb, krb, vtb);

  // full-D attention per batch: scores = (q/sqrt(128)) . k^T  (causal)
  gemm_nt<4, 1><<<dim3(16, 16, 2), 256, 0, stream>>>(
      qrb, krb, scoresB, nullptr, 2048, 2048, 2048, 4194304, 4194304, 4194304);
  softmax_causal<<<4096, 256, 0, stream>>>(scoresB, probsB);
  gemm_nt<0, 2><<<dim3(16, 16, 2), 256, 0, stream>>>(
      probsB, vtb, attnb, nullptr, 2048, 2048, 2048, 4194304, 4194304, 4194304);

  gemm_nt<1, 0><<<dim3(16, 32, 1), 256, 0, stream>>>(
      attnb, woq, hbuf, hidden, 4096, 2048, 2048, 0, 0, 0);

  // MLP weights (aliases of attention scratch — only safe after PV gemm)
  quantize_w<<<2048, 256, 0, stream>>>(wg, wgq, 16777216, scales, 4);
  quantize_w<<<2048, 256, 0, stream>>>(wu, wuq, 16777216, scales, 5);

  rmsnorm_k<<<4096, 256, 0, stream>>>(hbuf, ln2, ybuf);

  gemm_nt<0, 0><<<dim3(64, 32, 1), 256, 0, stream>>>(
      ybuf, wgq, gbuf, nullptr, 4096, 8192, 2048, 0, 0, 0);
  gemm_nt<2, 0><<<dim3(64, 32, 1), 256, 0, stream>>>(
      ybuf, wuq, gated, gbuf, 4096, 8192, 2048, 0, 0, 0);
  gemm_nt<3, 0><<<dim3(16, 32, 1), 256, 0, stream>>>(
      gated, wdq, (float*)d_out, hbuf, 4096, 2048, 8192, 0, 0, 0);
}

// Round 3
// 970.731 us; speedup vs baseline: 1.1393x; 1.1393x over previous
//
#include <hip/hip_runtime.h>
#include <stdint.h>

#define DEV __device__ __forceinline__

typedef __attribute__((ext_vector_type(8))) short short8;
typedef __attribute__((ext_vector_type(8))) __bf16 bf16x8;
typedef __attribute__((ext_vector_type(4))) float f32x4;

DEV unsigned short f2bf(float f) {
  union { float f; unsigned int u; } v; v.f = f;
  unsigned int r = v.u + 0x7fffu + ((v.u >> 16) & 1u);
  return (unsigned short)(r >> 16);
}
DEV float bf2f(unsigned short h) {
  union { unsigned int u; float f; } v; v.u = ((unsigned int)h) << 16;
  return v.f;
}
DEV f32x4 mfma16(short8 a, short8 b, f32x4 c) {
  return __builtin_amdgcn_mfma_f32_16x16x32_bf16(
      __builtin_bit_cast(bf16x8, a), __builtin_bit_cast(bf16x8, b), c, 0, 0, 0);
}
DEV void gload_lds16(const void* g, void* lds) {
  __builtin_amdgcn_global_load_lds(
      (const __attribute__((address_space(1))) void*)g,
      (__attribute__((address_space(3))) void*)lds, 16, 0, 0);
}

// ---------------- abs-mean scale ----------------
__global__ __launch_bounds__(256) void absmean_partial(
    const float* __restrict__ w, int n, float* __restrict__ partial) {
  const float4* w4 = (const float4*)w;
  int n4 = n >> 2;
  float s = 0.f;
  for (int i = blockIdx.x * 256 + threadIdx.x; i < n4; i += 256 * 256) {
    float4 v = w4[i];
    s += fabsf(v.x) + fabsf(v.y) + fabsf(v.z) + fabsf(v.w);
  }
#pragma unroll
  for (int m = 1; m < 64; m <<= 1) s += __shfl_xor(s, m);
  __shared__ float red[4];
  if ((threadIdx.x & 63) == 0) red[threadIdx.x >> 6] = s;
  __syncthreads();
  if (threadIdx.x == 0) partial[blockIdx.x] = red[0] + red[1] + red[2] + red[3];
}

__global__ __launch_bounds__(256) void absmean_final(
    const float* __restrict__ partial, float* __restrict__ scales) {
  __shared__ double red[256];
  const int m = blockIdx.x;
  red[threadIdx.x] = (double)partial[m * 256 + threadIdx.x];
  __syncthreads();
  for (int s = 128; s > 0; s >>= 1) {
    if (threadIdx.x < s) red[threadIdx.x] += red[threadIdx.x + s];
    __syncthreads();
  }
  if (threadIdx.x == 0) {
    const long long cnt = (m < 4) ? 4194304ll : 16777216ll;
    scales[m] = (float)(red[0] / (double)cnt);
  }
}

// ---------------- ternary quantize -> bf16 ----------------
__global__ __launch_bounds__(256) void quantize_w(
    const float* __restrict__ w, unsigned short* __restrict__ out, int n,
    const float* __restrict__ scales, int sidx) {
  const float sc = scales[sidx];
  const float inv = 1.f / (sc + 1e-5f);
  int n4 = n >> 2;
  for (int i = blockIdx.x * 256 + threadIdx.x; i < n4; i += 2048 * 256) {
    float4 v = ((const float4*)w)[i];
    ushort4 o;
    o.x = f2bf(fminf(fmaxf(rintf(v.x * inv), -1.f), 1.f) * sc);
    o.y = f2bf(fminf(fmaxf(rintf(v.y * inv), -1.f), 1.f) * sc);
    o.z = f2bf(fminf(fmaxf(rintf(v.z * inv), -1.f), 1.f) * sc);
    o.w = f2bf(fminf(fmaxf(rintf(v.w * inv), -1.f), 1.f) * sc);
    ((ushort4*)out)[i] = o;
  }
}

// ---------------- RMSNorm (f32 in -> bf16 out) ----------------
__global__ __launch_bounds__(256) void rmsnorm_k(
    const float* __restrict__ x, const float* __restrict__ wt,
    unsigned short* __restrict__ out) {
  const long long t = blockIdx.x;
  const float* xr = x + t * 2048;
  const int i0 = threadIdx.x * 8;
  float4 a = *(const float4*)(xr + i0);
  float4 b = *(const float4*)(xr + i0 + 4);
  float ss = a.x * a.x + a.y * a.y + a.z * a.z + a.w * a.w +
             b.x * b.x + b.y * b.y + b.z * b.z + b.w * b.w;
#pragma unroll
  for (int m = 1; m < 64; m <<= 1) ss += __shfl_xor(ss, m);
  __shared__ float red[4];
  if ((threadIdx.x & 63) == 0) red[threadIdx.x >> 6] = ss;
  __syncthreads();
  float tot = red[0] + red[1] + red[2] + red[3];
  float rs = rsqrtf(tot * (1.f / 2048.f) + 1e-5f);
  float4 wa = *(const float4*)(wt + i0);
  float4 wb = *(const float4*)(wt + i0 + 4);
  ushort4 o1, o2;
  o1.x = f2bf(a.x * wa.x * rs); o1.y = f2bf(a.y * wa.y * rs);
  o1.z = f2bf(a.z * wa.z * rs); o1.w = f2bf(a.w * wa.w * rs);
  o2.x = f2bf(b.x * wb.x * rs); o2.y = f2bf(b.y * wb.y * rs);
  o2.z = f2bf(b.z * wb.z * rs); o2.w = f2bf(b.w * wb.w * rs);
  *(ushort4*)(out + t * 2048 + i0) = o1;
  *(ushort4*)(out + t * 2048 + i0 + 4) = o2;
}

// ---------------- RoPE + V transpose ----------------
__global__ __launch_bounds__(256) void rope_k(
    const unsigned short* __restrict__ qkv, const float* __restrict__ cosT,
    const float* __restrict__ sinT, unsigned short* __restrict__ qr,
    unsigned short* __restrict__ kr, unsigned short* __restrict__ vt) {
  const long long gid = (long long)blockIdx.x * 256 + threadIdx.x;
  const int t = (int)(gid >> 10);
  const int r = (int)(gid & 1023);
  const int h = r >> 6, d = r & 63;
  const int s = t & 2047, b = t >> 11;
  const unsigned short* row = qkv + (long long)t * 6144;
  const float c = cosT[s * 128 + d], sn = sinT[s * 128 + d];
  const int col = h * 128 + d;
  const float SC = 0.08838834764831845f;  // 1/sqrt(128)
  float q1 = bf2f(row[col]), q2 = bf2f(row[col + 64]);
  float k1 = bf2f(row[2048 + col]), k2 = bf2f(row[2048 + col + 64]);
  long long ob = (long long)t * 2048 + col;
  qr[ob] = f2bf((q1 * c - q2 * sn) * SC);
  qr[ob + 64] = f2bf((q2 * c + q1 * sn) * SC);
  kr[ob] = f2bf(k1 * c - k2 * sn);
  kr[ob + 64] = f2bf(k2 * c + k1 * sn);
  vt[((long long)b * 2048 + col) * 2048 + s] = row[4096 + col];
  vt[((long long)b * 2048 + col + 64) * 2048 + s] = row[4096 + col + 64];
}

// ---------------- causal row softmax ----------------
__global__ __launch_bounds__(256) void softmax_causal(
    const float* __restrict__ scores, unsigned short* __restrict__ probs) {
  const int r = blockIdx.x;
  const int s = r & 2047;
  const float* src = scores + (long long)r * 2048;
  unsigned short* dst = probs + (long long)r * 2048;
  const int L = s + 1;
  __shared__ float red[4];
  float mx = -1e30f;
  for (int j = threadIdx.x; j < L; j += 256) mx = fmaxf(mx, src[j]);
#pragma unroll
  for (int m = 1; m < 64; m <<= 1) mx = fmaxf(mx, __shfl_xor(mx, m));
  if ((threadIdx.x & 63) == 0) red[threadIdx.x >> 6] = mx;
  __syncthreads();
  mx = fmaxf(fmaxf(red[0], red[1]), fmaxf(red[2], red[3]));
  float sum = 0.f;
  for (int j = threadIdx.x; j < L; j += 256) sum += __expf(src[j] - mx);
  __syncthreads();
#pragma unroll
  for (int m = 1; m < 64; m <<= 1) sum += __shfl_xor(sum, m);
  if ((threadIdx.x & 63) == 0) red[threadIdx.x >> 6] = sum;
  __syncthreads();
  const float inv = 1.f / (red[0] + red[1] + red[2] + red[3]);
  for (int j = threadIdx.x; j < 2048; j += 256)
    dst[j] = (j < L) ? f2bf(__expf(src[j] - mx) * inv) : (unsigned short)0;
}

// ---------------- old 128^2 NT GEMM (attention QK/PV only) ----------------
// EPI 0: bf16 out. 4: f32 raw. CAUSAL 1: block-skip. 2: K-limit.
template <int EPI, int CAUSAL>
__global__ __launch_bounds__(256) void gemm_nt(
    const unsigned short* __restrict__ A, const unsigned short* __restrict__ Bw,
    void* __restrict__ Cp, int M, int N, int K,
    long long sAz, long long sBz, long long sCz) {
  const long long m0 = (long long)blockIdx.y * 128;
  const long long n0 = (long long)blockIdx.x * 128;
  if (CAUSAL == 1 && n0 > m0 + 127) return;
  __shared__ __align__(16) unsigned short sA[2][128 * 32];
  __shared__ __align__(16) unsigned short sB[2][128 * 32];
  const int tid = threadIdx.x;
  const int w = tid >> 6, l = tid & 63;
  const long long z = blockIdx.z;
  A += z * sAz;
  Bw += z * sBz;
  const long long cofs = z * sCz;
  const int wr = w >> 1, wc = w & 1;
  const int lrow = l & 15, lk = (l >> 4) * 8;

  f32x4 acc[4][4] = {};
  int nk = K >> 5;
  if (CAUSAL == 2) nk = (int)((m0 + 128) >> 5);
  int cur = 0;

  auto stage = [&](int buf, int k0) {
#pragma unroll
    for (int i = 0; i < 2; ++i) {
      const int flat = (w * 2 + i) * 64 + l;
      const int row = flat >> 2;
      const int col = (flat & 3) * 8;
      gload_lds16(&A[(m0 + row) * K + k0 + col], (char*)&sA[buf][0] + (w * 2 + i) * 1024);
      gload_lds16(&Bw[(n0 + row) * K + k0 + col], (char*)&sB[buf][0] + (w * 2 + i) * 1024);
    }
  };

  stage(0, 0);
  __syncthreads();
  for (int kt = 0; kt < nk; ++kt) {
    if (kt + 1 < nk) stage(cur ^ 1, (kt + 1) << 5);
    short8 af[4], bfr[4];
#pragma unroll
    for (int m = 0; m < 4; ++m)
      af[m] = *(const short8*)&sA[cur][(wr * 64 + m * 16 + lrow) * 32 + lk];
#pragma unroll
    for (int n = 0; n < 4; ++n)
      bfr[n] = *(const short8*)&sB[cur][(wc * 64 + n * 16 + lrow) * 32 + lk];
#pragma unroll
    for (int m = 0; m < 4; ++m)
#pragma unroll
      for (int n = 0; n < 4; ++n)
        acc[m][n] = mfma16(af[m], bfr[n], acc[m][n]);
    __syncthreads();
    cur ^= 1;
  }

  const int orow = (l >> 4) * 4, ocol = l & 15;
#pragma unroll
  for (int m = 0; m < 4; ++m)
#pragma unroll
    for (int n = 0; n < 4; ++n)
#pragma unroll
      for (int r = 0; r < 4; ++r) {
        long long gr = m0 + wr * 64 + m * 16 + orow + r;
        long long gc = n0 + wc * 64 + n * 16 + ocol;
        long long idx = cofs + gr * N + gc;
        float v = acc[m][n][r];
        if (EPI == 0) ((unsigned short*)Cp)[idx] = f2bf(v);
        else ((float*)Cp)[idx] = v;
      }
}

// ---------------- 256^2 deep-pipelined NT GEMM ----------------
// 512 thr = 8 waves (2x4), wave tile 128x64. 4-slot ring of K-chunks (32 deep).
// LDS swizzle: col-chunk ^= (row>>1)&3 (both-sides involution, lane-constant).
// vmcnt(8) once per chunk (never 0 in loop), raw barriers, setprio on MFMA.
// EPI 0: bf16. 2: bf16 = Ep(bf16)*acc. 4: f32 raw at +z*zCout (split-K partial).
template <int EPI>
__global__ __launch_bounds__(512, 2) void gemm256(
    const unsigned short* __restrict__ A, const unsigned short* __restrict__ Bw,
    void* __restrict__ Cp, const void* __restrict__ Ep,
    int N, int K, int nbx, int kLen, int nChunks, long long zCout) {
  __shared__ __align__(16) unsigned short lds[4 * 2 * 8192];  // 128KB
  __shared__ __align__(16) unsigned short ldsDummy[512];      // 1KB sink
  const int tid = threadIdx.x;
  const int wid = tid >> 6, l = tid & 63;
  const int wr = wid >> 2, wcn = wid & 3;

  const int nwg = gridDim.x;            // divisible by 8
  const int wg = blockIdx.x;
  const int q8 = nwg >> 3;
  const int wgid = (wg & 7) * q8 + (wg >> 3);  // XCD-contiguous chunks
  const long long m0 = (long long)(wgid / nbx) * 256;
  const long long n0 = (long long)(wgid % nbx) * 256;
  const int z = blockIdx.z;
  const long long kbase = (long long)z * kLen;
  const long long zofs = (long long)z * zCout;

  // staging: per wave-instr i, LDS 16B-chunks c16=(wid*2+i)*64+l of a 16KB slot
  const int stRow = (l >> 2);                          // + (wid*2+i)*16
  const int stCol = (((l & 3) ^ ((l >> 3) & 3))) * 8;  // swizzled source col
  auto stage = [&](int chunk, int mat) {
    char* base = (char*)lds + (((chunk & 3) * 2 + mat) * 16384);
    const unsigned short* src = mat ? Bw : A;
    const long long rb = mat ? n0 : m0;
    if (chunk < nChunks) {
      const long long kcol = kbase + (long long)chunk * 32 + stCol;
#pragma unroll
      for (int i = 0; i < 2; ++i) {
        const int row = (wid * 2 + i) * 16 + stRow;
        gload_lds16(&src[(rb + row) * K + kcol], base + (wid * 2 + i) * 1024);
      }
    } else {
#pragma unroll
      for (int i = 0; i < 2; ++i) gload_lds16(&src[rb * K], (char*)ldsDummy);
    }
  };

  // lane-constant swizzled read offset pieces
  const int ar = l & 15;
  const int rj = ((l >> 4) ^ ((l >> 1) & 3)) << 4;  // swizzled 16B window

  f32x4 acc[8][4] = {};

  // prologue: chunks 0..2 in flight (12 loads); drain own A0,B0 shares
  stage(0, 0); stage(0, 1);
  stage(1, 0); stage(1, 1);
  stage(2, 0); stage(2, 1);
  asm volatile("s_waitcnt vmcnt(8)" ::: "memory");
  __builtin_amdgcn_s_barrier();

  for (int c = 0; c < nChunks; ++c) {
    const int slot = c & 3;
    const char* sA = (const char*)lds + (slot * 2 + 0) * 16384;
    const char* sB = (const char*)lds + (slot * 2 + 1) * 16384;
    short8 af[4], bf[4];
    // ---- phase 0: m-frags 0-3 ----
#pragma unroll
    for (int m = 0; m < 4; ++m)
      af[m] = *(const short8*)(sA + (wr * 128 + m * 16 + ar) * 64 + rj);
#pragma unroll
    for (int n = 0; n < 4; ++n)
      bf[n] = *(const short8*)(sB + (wcn * 64 + n * 16 + ar) * 64 + rj);
    stage(c + 3, 0);
    __builtin_amdgcn_s_barrier();
    asm volatile("s_waitcnt lgkmcnt(0)" ::: "memory");
    __builtin_amdgcn_sched_barrier(0);
    __builtin_amdgcn_s_setprio(1);
#pragma unroll
    for (int m = 0; m < 4; ++m)
#pragma unroll
      for (int n = 0; n < 4; ++n) acc[m][n] = mfma16(af[m], bf[n], acc[m][n]);
    __builtin_amdgcn_s_setprio(0);
    __builtin_amdgcn_s_barrier();
    // ---- phase 1: m-frags 4-7 (B frags reused) ----
#pragma unroll
    for (int m = 0; m < 4; ++m)
      af[m] = *(const short8*)(sA + (wr * 128 + (m + 4) * 16 + ar) * 64 + rj);
    stage(c + 3, 1);
    __builtin_amdgcn_s_barrier();
    asm volatile("s_waitcnt lgkmcnt(0)" ::: "memory");
    __builtin_amdgcn_sched_barrier(0);
    __builtin_amdgcn_s_setprio(1);
#pragma unroll
    for (int m = 0; m < 4; ++m)
#pragma unroll
      for (int n = 0; n < 4; ++n)
        acc[m + 4][n] = mfma16(af[m], bf[n], acc[m + 4][n]);
    __builtin_amdgcn_s_setprio(0);
    asm volatile("s_waitcnt vmcnt(8)" ::: "memory");  // next chunk landed (own share)
    __builtin_amdgcn_s_barrier();
  }
  asm volatile("s_waitcnt vmcnt(0)" ::: "memory");
  __builtin_amdgcn_s_barrier();

  const int orow = (l >> 4) * 4, ocol = l & 15;
#pragma unroll
  for (int m = 0; m < 8; ++m)
#pragma unroll
    for (int n = 0; n < 4; ++n)
#pragma unroll
      for (int r = 0; r < 4; ++r) {
        const long long gr = m0 + wr * 128 + m * 16 + orow + r;
        const long long gc = n0 + wcn * 64 + n * 16 + ocol;
        const long long idx = zofs + gr * N + gc;
        const float v = acc[m][n][r];
        if (EPI == 0) {
          ((unsigned short*)Cp)[idx] = f2bf(v);
        } else if (EPI == 2) {
          ((unsigned short*)Cp)[idx] = f2bf(bf2f(((const unsigned short*)Ep)[idx]) * v);
        } else {
          ((float*)Cp)[idx] = v;
        }
      }
}

// ---------------- split-K combine: out = ep + p[0:n] + p[n:2n] ----------------
__global__ __launch_bounds__(256) void combine2(
    const float* __restrict__ ep, const float* __restrict__ p,
    float* __restrict__ out, long long n4) {
  const float4* e4 = (const float4*)ep;
  const float4* p4 = (const float4*)p;
  float4* o4 = (float4*)out;
  for (long long i = blockIdx.x * 256 + threadIdx.x; i < n4; i += 2048 * 256) {
    float4 a = e4[i], b = p4[i], c = p4[i + n4];
    float4 o;
    o.x = a.x + b.x + c.x; o.y = a.y + b.y + c.y;
    o.z = a.z + b.z + c.z; o.w = a.w + b.w + c.w;
    o4[i] = o;
  }
}

extern "C" void kernel_launch(void* const* d_in, const int* in_sizes, int n_in,
                              void* d_out, int out_size, void* d_ws, size_t ws_size,
                              hipStream_t stream) {
  (void)in_sizes; (void)n_in; (void)out_size; (void)ws_size;
  const float* hidden = (const float*)d_in[0];
  const float* cosT = (const float*)d_in[2];
  const float* sinT = (const float*)d_in[3];
  const float* wq = (const float*)d_in[4];
  const float* wk = (const float*)d_in[5];
  const float* wv = (const float*)d_in[6];
  const float* wo = (const float*)d_in[7];
  const float* wg = (const float*)d_in[8];
  const float* wu = (const float*)d_in[9];
  const float* wd = (const float*)d_in[10];
  const float* ln1 = (const float*)d_in[11];
  const float* ln2 = (const float*)d_in[12];

  const size_t MB = 1ull << 20;
  char* ws = (char*)d_ws;
  // phase-1 (QKV) region
  unsigned short* xn    = (unsigned short*)(ws + 0);        // 16MB [0,16)
  unsigned short* wqkvq = (unsigned short*)(ws + 16 * MB);  // 24MB [16,40)
  unsigned short* qkv   = (unsigned short*)(ws + 40 * MB);  // 48MB [40,88)
  unsigned short* qrb   = (unsigned short*)(ws + 88 * MB);  // 16MB
  unsigned short* krb   = (unsigned short*)(ws + 104 * MB); // 16MB
  unsigned short* vtb   = (unsigned short*)(ws + 120 * MB); // 16MB
  // attention aliases
  float*          scoresB = (float*)(ws + 0);               // 32MB (xn+wqkvq dead)
  unsigned short* probsB  = (unsigned short*)(ws + 40 * MB);// 16MB (qkv dead)
  // split-K partials (O then D) — [0,64), dead regions at time of use
  float*          part   = (float*)(ws + 0);                // 64MB
  // MLP aliases
  unsigned short* wgq   = (unsigned short*)(ws + 0);        // 32MB
  unsigned short* wuq   = (unsigned short*)(ws + 32 * MB);  // 32MB
  unsigned short* gbuf  = (unsigned short*)(ws + 64 * MB);  // 64MB
  // persistent region
  unsigned short* attnb = (unsigned short*)(ws + 136 * MB); // 16MB
  unsigned short* woq   = (unsigned short*)(ws + 152 * MB); // 8MB
  float*          hbuf  = (float*)(ws + 160 * MB);          // 32MB
  unsigned short* ybuf  = (unsigned short*)(ws + 192 * MB); // 16MB
  unsigned short* gated = (unsigned short*)(ws + 208 * MB); // 64MB
  unsigned short* wdq   = (unsigned short*)(ws + 272 * MB); // 32MB
  float* wspart         = (float*)(ws + 304 * MB);
  float* scales         = (float*)(ws + 304 * MB + 16384);

  const float* wptr[7] = {wq, wk, wv, wo, wg, wu, wd};
  const int wn[7] = {4194304, 4194304, 4194304, 4194304, 16777216, 16777216, 16777216};
  for (int m = 0; m < 7; ++m)
    absmean_partial<<<256, 256, 0, stream>>>(wptr[m], wn[m], wspart + m * 256);
  absmean_final<<<7, 256, 0, stream>>>(wspart, scales);

  quantize_w<<<2048, 256, 0, stream>>>(wo, woq, 4194304, scales, 3);
  quantize_w<<<2048, 256, 0, stream>>>(wd, wdq, 16777216, scales, 6);

  rmsnorm_k<<<4096, 256, 0, stream>>>(hidden, ln1, xn);

  quantize_w<<<2048, 256, 0, stream>>>(wq, wqkvq, 4194304, scales, 0);
  quantize_w<<<2048, 256, 0, stream>>>(wk, wqkvq + 4194304, 4194304, scales, 1);
  quantize_w<<<2048, 256, 0, stream>>>(wv, wqkvq + 8388608, 4194304, scales, 2);

  // QKV: [4096x6144x2048]  grid 16*24=384
  gemm256<0><<<dim3(384, 1, 1), 512, 0, stream>>>(
      xn, wqkvq, qkv, nullptr, 6144, 2048, 24, 2048, 64, 0);

  rope_k<<<16384, 256, 0, stream>>>(qkv, cosT, sinT, qrb, krb, vtb);

  // attention (full-D per batch, causal)
  gemm_nt<4, 1><<<dim3(16, 16, 2), 256, 0, stream>>>(
      qrb, krb, scoresB, 2048, 2048, 2048, 4194304, 4194304, 4194304);
  softmax_causal<<<4096, 256, 0, stream>>>(scoresB, probsB);
  gemm_nt<0, 2><<<dim3(16, 16, 2), 256, 0, stream>>>(
      probsB, vtb, attnb, 2048, 2048, 2048, 4194304, 4194304, 4194304);

  // O-proj: split-K=2 partials -> combine with residual
  gemm256<4><<<dim3(128, 1, 2), 512, 0, stream>>>(
      attnb, woq, part, nullptr, 2048, 2048, 8, 1024, 32, 8388608);
  combine2<<<2048, 256, 0, stream>>>(hidden, part, hbuf, 2097152);

  // MLP weights (alias attention scratch — safe after O-combine)
  quantize_w<<<2048, 256, 0, stream>>>(wg, wgq, 16777216, scales, 4);
  quantize_w<<<2048, 256, 0, stream>>>(wu, wuq, 16777216, scales, 5);

  rmsnorm_k<<<4096, 256, 0, stream>>>(hbuf, ln2, ybuf);

  // G, U: [4096x8192x2048]  grid 16*32=512
  gemm256<0><<<dim3(512, 1, 1), 512, 0, stream>>>(
      ybuf, wgq, gbuf, nullptr, 8192, 2048, 32, 2048, 64, 0);
  gemm256<2><<<dim3(512, 1, 1), 512, 0, stream>>>(
      ybuf, wuq, gated, gbuf, 8192, 2048, 32, 2048, 64, 0);

  // D: [4096x2048x8192] split-K=2 -> combine with h residual into d_out
  gemm256<4><<<dim3(128, 1, 2), 512, 0, stream>>>(
      gated, wdq, part, nullptr, 2048, 8192, 8, 4096, 128, 8388608);
  combine2<<<2048, 256, 0, stream>>>(hbuf, part, (float*)d_out, 2097152);
}

// Round 4
// 880.018 us; speedup vs baseline: 1.2567x; 1.1031x over previous
//
#include <hip/hip_runtime.h>
#include <stdint.h>

#define DEV __device__ __forceinline__

typedef __attribute__((ext_vector_type(8))) short short8;
typedef __attribute__((ext_vector_type(8))) __bf16 bf16x8;
typedef __attribute__((ext_vector_type(4))) float f32x4;

DEV unsigned short f2bf(float f) {
  union { float f; unsigned int u; } v; v.f = f;
  unsigned int r = v.u + 0x7fffu + ((v.u >> 16) & 1u);
  return (unsigned short)(r >> 16);
}
DEV float bf2f(unsigned short h) {
  union { unsigned int u; float f; } v; v.u = ((unsigned int)h) << 16;
  return v.f;
}
DEV f32x4 mfma16(short8 a, short8 b, f32x4 c) {
  return __builtin_amdgcn_mfma_f32_16x16x32_bf16(
      __builtin_bit_cast(bf16x8, a), __builtin_bit_cast(bf16x8, b), c, 0, 0, 0);
}
DEV void gload_lds16(const void* g, void* lds) {
  __builtin_amdgcn_global_load_lds(
      (const __attribute__((address_space(1))) void*)g,
      (__attribute__((address_space(3))) void*)lds, 16, 0, 0);
}

struct MArgs {
  const float* src[7];
  unsigned short* dst[7];
  int n[7];
  int sidx[7];
};

// ---------------- abs-mean partial (all matrices, one launch) ----------------
__global__ __launch_bounds__(256) void absmean_partial_multi(
    MArgs a, float* __restrict__ partial) {
  const int m = blockIdx.y;
  const float4* w4 = (const float4*)a.src[m];
  const int n4 = a.n[m] >> 2;
  float s = 0.f;
  for (int i = blockIdx.x * 256 + threadIdx.x; i < n4; i += 1024 * 256) {
    float4 v = w4[i];
    s += fabsf(v.x) + fabsf(v.y) + fabsf(v.z) + fabsf(v.w);
  }
#pragma unroll
  for (int mm = 1; mm < 64; mm <<= 1) s += __shfl_xor(s, mm);
  __shared__ float red[4];
  if ((threadIdx.x & 63) == 0) red[threadIdx.x >> 6] = s;
  __syncthreads();
  if (threadIdx.x == 0)
    partial[m * 1024 + blockIdx.x] = red[0] + red[1] + red[2] + red[3];
}

__global__ __launch_bounds__(256) void absmean_final(
    const float* __restrict__ partial, float* __restrict__ scales) {
  __shared__ double red[256];
  const int m = blockIdx.x;
  double s = 0.0;
  for (int i = threadIdx.x; i < 1024; i += 256) s += (double)partial[m * 1024 + i];
  red[threadIdx.x] = s;
  __syncthreads();
  for (int t = 128; t > 0; t >>= 1) {
    if (threadIdx.x < t) red[threadIdx.x] += red[threadIdx.x + t];
    __syncthreads();
  }
  if (threadIdx.x == 0) {
    const long long cnt = (m < 4) ? 4194304ll : 16777216ll;
    scales[m] = (float)(red[0] / (double)cnt);
  }
}

// ---------------- ternary quantize -> bf16 (batched) ----------------
__global__ __launch_bounds__(256) void quantize_multi(
    MArgs a, const float* __restrict__ scales) {
  const int m = blockIdx.y;
  const float sc = scales[a.sidx[m]];
  const float inv = 1.f / (sc + 1e-5f);
  const float4* src = (const float4*)a.src[m];
  ushort4* dst = (ushort4*)a.dst[m];
  const int n4 = a.n[m] >> 2;
  for (int i = blockIdx.x * 256 + threadIdx.x; i < n4; i += 2048 * 256) {
    float4 v = src[i];
    ushort4 o;
    o.x = f2bf(fminf(fmaxf(rintf(v.x * inv), -1.f), 1.f) * sc);
    o.y = f2bf(fminf(fmaxf(rintf(v.y * inv), -1.f), 1.f) * sc);
    o.z = f2bf(fminf(fmaxf(rintf(v.z * inv), -1.f), 1.f) * sc);
    o.w = f2bf(fminf(fmaxf(rintf(v.w * inv), -1.f), 1.f) * sc);
    dst[i] = o;
  }
}

// ---------------- RMSNorm (f32 in -> bf16 out) ----------------
__global__ __launch_bounds__(256) void rmsnorm_k(
    const float* __restrict__ x, const float* __restrict__ wt,
    unsigned short* __restrict__ out) {
  const long long t = blockIdx.x;
  const float* xr = x + t * 2048;
  const int i0 = threadIdx.x * 8;
  float4 a = *(const float4*)(xr + i0);
  float4 b = *(const float4*)(xr + i0 + 4);
  float ss = a.x * a.x + a.y * a.y + a.z * a.z + a.w * a.w +
             b.x * b.x + b.y * b.y + b.z * b.z + b.w * b.w;
#pragma unroll
  for (int m = 1; m < 64; m <<= 1) ss += __shfl_xor(ss, m);
  __shared__ float red[4];
  if ((threadIdx.x & 63) == 0) red[threadIdx.x >> 6] = ss;
  __syncthreads();
  float tot = red[0] + red[1] + red[2] + red[3];
  float rs = rsqrtf(tot * (1.f / 2048.f) + 1e-5f);
  float4 wa = *(const float4*)(wt + i0);
  float4 wb = *(const float4*)(wt + i0 + 4);
  ushort4 o1, o2;
  o1.x = f2bf(a.x * wa.x * rs); o1.y = f2bf(a.y * wa.y * rs);
  o1.z = f2bf(a.z * wa.z * rs); o1.w = f2bf(a.w * wa.w * rs);
  o2.x = f2bf(b.x * wb.x * rs); o2.y = f2bf(b.y * wb.y * rs);
  o2.z = f2bf(b.z * wb.z * rs); o2.w = f2bf(b.w * wb.w * rs);
  *(ushort4*)(out + t * 2048 + i0) = o1;
  *(ushort4*)(out + t * 2048 + i0 + 4) = o2;
}

// ---------------- RoPE + V transpose ----------------
__global__ __launch_bounds__(256) void rope_k(
    const unsigned short* __restrict__ qkv, const float* __restrict__ cosT,
    const float* __restrict__ sinT, unsigned short* __restrict__ qr,
    unsigned short* __restrict__ kr, unsigned short* __restrict__ vt) {
  const long long gid = (long long)blockIdx.x * 256 + threadIdx.x;
  const int t = (int)(gid >> 10);
  const int r = (int)(gid & 1023);
  const int h = r >> 6, d = r & 63;
  const int s = t & 2047, b = t >> 11;
  const unsigned short* row = qkv + (long long)t * 6144;
  const float c = cosT[s * 128 + d], sn = sinT[s * 128 + d];
  const int col = h * 128 + d;
  const float SC = 0.08838834764831845f;  // 1/sqrt(128)
  float q1 = bf2f(row[col]), q2 = bf2f(row[col + 64]);
  float k1 = bf2f(row[2048 + col]), k2 = bf2f(row[2048 + col + 64]);
  long long ob = (long long)t * 2048 + col;
  qr[ob] = f2bf((q1 * c - q2 * sn) * SC);
  qr[ob + 64] = f2bf((q2 * c + q1 * sn) * SC);
  kr[ob] = f2bf(k1 * c - k2 * sn);
  kr[ob + 64] = f2bf(k2 * c + k1 * sn);
  vt[((long long)b * 2048 + col) * 2048 + s] = row[4096 + col];
  vt[((long long)b * 2048 + col + 64) * 2048 + s] = row[4096 + col + 64];
}

// ---------------- causal row softmax ----------------
__global__ __launch_bounds__(256) void softmax_causal(
    const float* __restrict__ scores, unsigned short* __restrict__ probs) {
  const int r = blockIdx.x;
  const int s = r & 2047;
  const float* src = scores + (long long)r * 2048;
  unsigned short* dst = probs + (long long)r * 2048;
  const int L = s + 1;
  __shared__ float red[4];
  float mx = -1e30f;
  for (int j = threadIdx.x; j < L; j += 256) mx = fmaxf(mx, src[j]);
#pragma unroll
  for (int m = 1; m < 64; m <<= 1) mx = fmaxf(mx, __shfl_xor(mx, m));
  if ((threadIdx.x & 63) == 0) red[threadIdx.x >> 6] = mx;
  __syncthreads();
  mx = fmaxf(fmaxf(red[0], red[1]), fmaxf(red[2], red[3]));
  float sum = 0.f;
  for (int j = threadIdx.x; j < L; j += 256) sum += __expf(src[j] - mx);
  __syncthreads();
#pragma unroll
  for (int m = 1; m < 64; m <<= 1) sum += __shfl_xor(sum, m);
  if ((threadIdx.x & 63) == 0) red[threadIdx.x >> 6] = sum;
  __syncthreads();
  const float inv = 1.f / (red[0] + red[1] + red[2] + red[3]);
  for (int j = threadIdx.x; j < 2048; j += 256)
    dst[j] = (j < L) ? f2bf(__expf(src[j] - mx) * inv) : (unsigned short)0;
}

// ---------------- old 128^2 NT GEMM (attention QK/PV only) ----------------
template <int EPI, int CAUSAL>
__global__ __launch_bounds__(256) void gemm_nt(
    const unsigned short* __restrict__ A, const unsigned short* __restrict__ Bw,
    void* __restrict__ Cp, int M, int N, int K,
    long long sAz, long long sBz, long long sCz) {
  const long long m0 = (long long)blockIdx.y * 128;
  const long long n0 = (long long)blockIdx.x * 128;
  if (CAUSAL == 1 && n0 > m0 + 127) return;
  __shared__ __align__(16) unsigned short sA[2][128 * 32];
  __shared__ __align__(16) unsigned short sB[2][128 * 32];
  const int tid = threadIdx.x;
  const int w = tid >> 6, l = tid & 63;
  const long long z = blockIdx.z;
  A += z * sAz;
  Bw += z * sBz;
  const long long cofs = z * sCz;
  const int wr = w >> 1, wc = w & 1;
  const int lrow = l & 15, lk = (l >> 4) * 8;

  f32x4 acc[4][4] = {};
  int nk = K >> 5;
  if (CAUSAL == 2) nk = (int)((m0 + 128) >> 5);
  int cur = 0;

  auto stage = [&](int buf, int k0) {
#pragma unroll
    for (int i = 0; i < 2; ++i) {
      const int flat = (w * 2 + i) * 64 + l;
      const int row = flat >> 2;
      const int col = (flat & 3) * 8;
      gload_lds16(&A[(m0 + row) * K + k0 + col], (char*)&sA[buf][0] + (w * 2 + i) * 1024);
      gload_lds16(&Bw[(n0 + row) * K + k0 + col], (char*)&sB[buf][0] + (w * 2 + i) * 1024);
    }
  };

  stage(0, 0);
  __syncthreads();
  for (int kt = 0; kt < nk; ++kt) {
    if (kt + 1 < nk) stage(cur ^ 1, (kt + 1) << 5);
    short8 af[4], bfr[4];
#pragma unroll
    for (int m = 0; m < 4; ++m)
      af[m] = *(const short8*)&sA[cur][(wr * 64 + m * 16 + lrow) * 32 + lk];
#pragma unroll
    for (int n = 0; n < 4; ++n)
      bfr[n] = *(const short8*)&sB[cur][(wc * 64 + n * 16 + lrow) * 32 + lk];
#pragma unroll
    for (int m = 0; m < 4; ++m)
#pragma unroll
      for (int n = 0; n < 4; ++n)
        acc[m][n] = mfma16(af[m], bfr[n], acc[m][n]);
    __syncthreads();
    cur ^= 1;
  }

  const int orow = (l >> 4) * 4, ocol = l & 15;
#pragma unroll
  for (int m = 0; m < 4; ++m)
#pragma unroll
    for (int n = 0; n < 4; ++n)
#pragma unroll
      for (int r = 0; r < 4; ++r) {
        long long gr = m0 + wr * 64 + m * 16 + orow + r;
        long long gc = n0 + wc * 64 + n * 16 + ocol;
        long long idx = cofs + gr * N + gc;
        float v = acc[m][n][r];
        if (EPI == 0) ((unsigned short*)Cp)[idx] = f2bf(v);
        else ((float*)Cp)[idx] = v;
      }
}

// ---------------- 256^2 deep-pipelined NT GEMM ----------------
// 8 waves (2x4), wave tile 128x64, 4-slot K-chunk ring, counted vmcnt,
// swizzled LDS, 2D-brick XCD scheduling (4x8 bricks per 32 blocks).
template <int EPI>
__global__ __launch_bounds__(512, 2) void gemm256(
    const unsigned short* __restrict__ A, const unsigned short* __restrict__ Bw,
    void* __restrict__ Cp, const void* __restrict__ Ep,
    int N, int K, int nbx, int kLen, int nChunks, long long zCout) {
  __shared__ __align__(16) unsigned short lds[4 * 2 * 8192];  // 128KB
  __shared__ __align__(16) unsigned short ldsDummy[512];      // 1KB sink
  const int tid = threadIdx.x;
  const int wid = tid >> 6, l = tid & 63;
  const int wr = wid >> 2, wcn = wid & 3;

  // 2D-brick schedule: XCD-contiguous lin ids traverse 4x8 block bricks so the
  // ~32 concurrent blocks per XCD share 4 A-panels + 8 B-panels (L2 locality).
  const int nwg = gridDim.x;  // divisible by 32; nbx divisible by 8
  const int q8 = nwg >> 3;
  const int lin = (blockIdx.x & 7) * q8 + (blockIdx.x >> 3);
  const int t32 = lin >> 5, r32 = lin & 31;
  const int tpr = nbx >> 3;
  const int tm = t32 / tpr, tn = t32 - tm * tpr;
  const long long m0 = (long long)(tm * 4 + (r32 >> 3)) * 256;
  const long long n0 = (long long)(tn * 8 + (r32 & 7)) * 256;
  const int z = blockIdx.z;
  const long long kbase = (long long)z * kLen;
  const long long zofs = (long long)z * zCout;

  const int stRow = (l >> 2);
  const int stCol = (((l & 3) ^ ((l >> 3) & 3))) * 8;  // pre-swizzled source col
  auto stage = [&](int chunk, int mat) {
    char* base = (char*)lds + (((chunk & 3) * 2 + mat) * 16384);
    const unsigned short* src = mat ? Bw : A;
    const long long rb = mat ? n0 : m0;
    if (chunk < nChunks) {
      const long long kcol = kbase + (long long)chunk * 32 + stCol;
#pragma unroll
      for (int i = 0; i < 2; ++i) {
        const int row = (wid * 2 + i) * 16 + stRow;
        gload_lds16(&src[(rb + row) * K + kcol], base + (wid * 2 + i) * 1024);
      }
    } else {
#pragma unroll
      for (int i = 0; i < 2; ++i) gload_lds16(&src[rb * K], (char*)ldsDummy);
    }
  };

  const int ar = l & 15;
  const int rj = ((l >> 4) ^ ((l >> 1) & 3)) << 4;  // swizzled 16B window

  f32x4 acc[8][4] = {};

  stage(0, 0); stage(0, 1);
  stage(1, 0); stage(1, 1);
  stage(2, 0); stage(2, 1);
  asm volatile("s_waitcnt vmcnt(8)" ::: "memory");
  __builtin_amdgcn_s_barrier();

  for (int c = 0; c < nChunks; ++c) {
    const int slot = c & 3;
    const char* sA = (const char*)lds + (slot * 2 + 0) * 16384;
    const char* sB = (const char*)lds + (slot * 2 + 1) * 16384;
    short8 af[4], bf[4];
    // ---- phase 0: m-frags 0-3 ----
#pragma unroll
    for (int m = 0; m < 4; ++m)
      af[m] = *(const short8*)(sA + (wr * 128 + m * 16 + ar) * 64 + rj);
#pragma unroll
    for (int n = 0; n < 4; ++n)
      bf[n] = *(const short8*)(sB + (wcn * 64 + n * 16 + ar) * 64 + rj);
    stage(c + 3, 0);
    __builtin_amdgcn_s_barrier();
    asm volatile("s_waitcnt lgkmcnt(0)" ::: "memory");
    __builtin_amdgcn_sched_barrier(0);
    __builtin_amdgcn_s_setprio(1);
#pragma unroll
    for (int m = 0; m < 4; ++m)
#pragma unroll
      for (int n = 0; n < 4; ++n) acc[m][n] = mfma16(af[m], bf[n], acc[m][n]);
    __builtin_amdgcn_s_setprio(0);
    __builtin_amdgcn_s_barrier();
    // ---- phase 1: m-frags 4-7 ----
#pragma unroll
    for (int m = 0; m < 4; ++m)
      af[m] = *(const short8*)(sA + (wr * 128 + (m + 4) * 16 + ar) * 64 + rj);
    stage(c + 3, 1);
    __builtin_amdgcn_s_barrier();
    asm volatile("s_waitcnt lgkmcnt(0)" ::: "memory");
    __builtin_amdgcn_sched_barrier(0);
    __builtin_amdgcn_s_setprio(1);
#pragma unroll
    for (int m = 0; m < 4; ++m)
#pragma unroll
      for (int n = 0; n < 4; ++n)
        acc[m + 4][n] = mfma16(af[m], bf[n], acc[m + 4][n]);
    __builtin_amdgcn_s_setprio(0);
    asm volatile("s_waitcnt vmcnt(8)" ::: "memory");
    __builtin_amdgcn_s_barrier();
  }
  asm volatile("s_waitcnt vmcnt(0)" ::: "memory");
  __builtin_amdgcn_s_barrier();

  const int orow = (l >> 4) * 4, ocol = l & 15;
#pragma unroll
  for (int m = 0; m < 8; ++m)
#pragma unroll
    for (int n = 0; n < 4; ++n)
#pragma unroll
      for (int r = 0; r < 4; ++r) {
        const long long gr = m0 + wr * 128 + m * 16 + orow + r;
        const long long gc = n0 + wcn * 64 + n * 16 + ocol;
        const long long idx = zofs + gr * N + gc;
        const float v = acc[m][n][r];
        if (EPI == 0) {
          ((unsigned short*)Cp)[idx] = f2bf(v);
        } else if (EPI == 2) {
          ((unsigned short*)Cp)[idx] = f2bf(bf2f(((const unsigned short*)Ep)[idx]) * v);
        } else {
          ((float*)Cp)[idx] = v;
        }
      }
}

// ---------------- split-K combine ----------------
__global__ __launch_bounds__(256) void combine2(
    const float* __restrict__ ep, const float* __restrict__ p,
    float* __restrict__ out, long long n4) {
  const float4* e4 = (const float4*)ep;
  const float4* p4 = (const float4*)p;
  float4* o4 = (float4*)out;
  for (long long i = blockIdx.x * 256 + threadIdx.x; i < n4; i += 2048 * 256) {
    float4 a = e4[i], b = p4[i], c = p4[i + n4];
    float4 o;
    o.x = a.x + b.x + c.x; o.y = a.y + b.y + c.y;
    o.z = a.z + b.z + c.z; o.w = a.w + b.w + c.w;
    o4[i] = o;
  }
}

extern "C" void kernel_launch(void* const* d_in, const int* in_sizes, int n_in,
                              void* d_out, int out_size, void* d_ws, size_t ws_size,
                              hipStream_t stream) {
  (void)in_sizes; (void)n_in; (void)out_size; (void)ws_size;
  const float* hidden = (const float*)d_in[0];
  const float* cosT = (const float*)d_in[2];
  const float* sinT = (const float*)d_in[3];
  const float* wq = (const float*)d_in[4];
  const float* wk = (const float*)d_in[5];
  const float* wv = (const float*)d_in[6];
  const float* wo = (const float*)d_in[7];
  const float* wg = (const float*)d_in[8];
  const float* wu = (const float*)d_in[9];
  const float* wd = (const float*)d_in[10];
  const float* ln1 = (const float*)d_in[11];
  const float* ln2 = (const float*)d_in[12];

  const size_t MB = 1ull << 20;
  char* ws = (char*)d_ws;
  unsigned short* xn    = (unsigned short*)(ws + 0);        // 16MB
  unsigned short* wqkvq = (unsigned short*)(ws + 16 * MB);  // 24MB
  unsigned short* qkv   = (unsigned short*)(ws + 40 * MB);  // 48MB
  unsigned short* qrb   = (unsigned short*)(ws + 88 * MB);  // 16MB
  unsigned short* krb   = (unsigned short*)(ws + 104 * MB); // 16MB
  unsigned short* vtb   = (unsigned short*)(ws + 120 * MB); // 16MB
  float*          scoresB = (float*)(ws + 0);               // 32MB alias
  unsigned short* probsB  = (unsigned short*)(ws + 40 * MB);// 16MB alias
  float*          part   = (float*)(ws + 0);                // 64MB alias
  unsigned short* wgq   = (unsigned short*)(ws + 0);        // 32MB alias
  unsigned short* wuq   = (unsigned short*)(ws + 32 * MB);  // 32MB alias
  unsigned short* gbuf  = (unsigned short*)(ws + 64 * MB);  // 64MB alias
  unsigned short* attnb = (unsigned short*)(ws + 136 * MB); // 16MB
  unsigned short* woq   = (unsigned short*)(ws + 152 * MB); // 8MB
  float*          hbuf  = (float*)(ws + 160 * MB);          // 32MB
  unsigned short* ybuf  = (unsigned short*)(ws + 192 * MB); // 16MB
  unsigned short* gated = (unsigned short*)(ws + 208 * MB); // 64MB
  unsigned short* wdq   = (unsigned short*)(ws + 272 * MB); // 32MB
  float* wspart         = (float*)(ws + 304 * MB);          // 28KB
  float* scales         = (float*)(ws + 304 * MB + 32768);

  // --- scales (one launch for all 7 partials) ---
  MArgs am;
  am.src[0] = wq; am.src[1] = wk; am.src[2] = wv; am.src[3] = wo;
  am.src[4] = wg; am.src[5] = wu; am.src[6] = wd;
  am.n[0] = am.n[1] = am.n[2] = am.n[3] = 4194304;
  am.n[4] = am.n[5] = am.n[6] = 16777216;
  for (int i = 0; i < 7; ++i) { am.dst[i] = nullptr; am.sidx[i] = i; }
  absmean_partial_multi<<<dim3(1024, 7), 256, 0, stream>>>(am, wspart);
  absmean_final<<<7, 256, 0, stream>>>(wspart, scales);

  // --- early quantize: wq,wk,wv -> wqkvq, wo -> woq, wd -> wdq (one launch) ---
  MArgs qe;
  qe.src[0] = wq; qe.dst[0] = wqkvq;            qe.n[0] = 4194304;  qe.sidx[0] = 0;
  qe.src[1] = wk; qe.dst[1] = wqkvq + 4194304;  qe.n[1] = 4194304;  qe.sidx[1] = 1;
  qe.src[2] = wv; qe.dst[2] = wqkvq + 8388608;  qe.n[2] = 4194304;  qe.sidx[2] = 2;
  qe.src[3] = wo; qe.dst[3] = woq;              qe.n[3] = 4194304;  qe.sidx[3] = 3;
  qe.src[4] = wd; qe.dst[4] = wdq;              qe.n[4] = 16777216; qe.sidx[4] = 6;
  qe.src[5] = wq; qe.dst[5] = nullptr; qe.n[5] = 0; qe.sidx[5] = 0;
  qe.src[6] = wq; qe.dst[6] = nullptr; qe.n[6] = 0; qe.sidx[6] = 0;
  quantize_multi<<<dim3(2048, 5), 256, 0, stream>>>(qe, scales);

  rmsnorm_k<<<4096, 256, 0, stream>>>(hidden, ln1, xn);

  // QKV: [4096x6144x2048], grid 384
  gemm256<0><<<dim3(384, 1, 1), 512, 0, stream>>>(
      xn, wqkvq, qkv, nullptr, 6144, 2048, 24, 2048, 64, 0);

  rope_k<<<16384, 256, 0, stream>>>(qkv, cosT, sinT, qrb, krb, vtb);

  // attention (full-D per batch, causal)
  gemm_nt<4, 1><<<dim3(16, 16, 2), 256, 0, stream>>>(
      qrb, krb, scoresB, 2048, 2048, 2048, 4194304, 4194304, 4194304);
  softmax_causal<<<4096, 256, 0, stream>>>(scoresB, probsB);
  gemm_nt<0, 2><<<dim3(16, 16, 2), 256, 0, stream>>>(
      probsB, vtb, attnb, 2048, 2048, 2048, 4194304, 4194304, 4194304);

  // O-proj: split-K=2 -> combine with residual
  gemm256<4><<<dim3(128, 1, 2), 512, 0, stream>>>(
      attnb, woq, part, nullptr, 2048, 2048, 8, 1024, 32, 8388608);
  combine2<<<2048, 256, 0, stream>>>(hidden, part, hbuf, 2097152);

  // late quantize: wg, wu (one launch; aliases attention scratch)
  MArgs ql;
  ql.src[0] = wg; ql.dst[0] = wgq; ql.n[0] = 16777216; ql.sidx[0] = 4;
  ql.src[1] = wu; ql.dst[1] = wuq; ql.n[1] = 16777216; ql.sidx[1] = 5;
  for (int i = 2; i < 7; ++i) { ql.src[i] = wg; ql.dst[i] = nullptr; ql.n[i] = 0; ql.sidx[i] = 0; }
  quantize_multi<<<dim3(2048, 2), 256, 0, stream>>>(ql, scales);

  rmsnorm_k<<<4096, 256, 0, stream>>>(hbuf, ln2, ybuf);

  // G, U: [4096x8192x2048], grid 512
  gemm256<0><<<dim3(512, 1, 1), 512, 0, stream>>>(
      ybuf, wgq, gbuf, nullptr, 8192, 2048, 32, 2048, 64, 0);
  gemm256<2><<<dim3(512, 1, 1), 512, 0, stream>>>(
      ybuf, wuq, gated, gbuf, 8192, 2048, 32, 2048, 64, 0);

  // D: [4096x2048x8192] split-K=2 -> combine into d_out
  gemm256<4><<<dim3(128, 1, 2), 512, 0, stream>>>(
      gated, wdq, part, nullptr, 2048, 8192, 8, 4096, 128, 8388608);
  combine2<<<2048, 256, 0, stream>>>(hbuf, part, (float*)d_out, 2097152);
}